// Round 2
// baseline (1333.698 us; speedup 1.0000x reference)
//
#include <hip/hip_runtime.h>
#include <math.h>

#define Bn 32
#define Cn 256
#define Hn 64
#define Wn 64
#define MIP 8
#define OUP 256
#define BN_EPS 1e-5f

typedef float vfloat4 __attribute__((ext_vector_type(4)));  // native vec for NT ld/st

// ---------------------------------------------------------------------------
// Kernel 1: per-(b,c) stats -> A[b][c][s], s in [0,128)
//   s<64:  a_h[h] = (rowsum[h] + softmax_h(rowmax)[h]) / 64
//   s>=64: a_w[w] = (colsum[w] + softmax_w(colmax)[w]) / 64
// (uses: mean_W(bias_h*bias_w) = bias_h/64 since softmax_w sums to 1)
// NEW in R2: gates epilogue fused via last-block-per-b pattern. The 256th
// block to finish for its b computes ys[8][128] (BN+hswish) and all 256 gate
// rows g[b][c][128] = sigmoid(W2 ys). Removes the separate gates dispatch +
// one graph-node boundary; epilogue (~3-5 us on 32 blocks) overlaps the
// stats tail. Device-scope release/acquire: store A -> __threadfence() ->
// atomicAdd(cnt[b]); finisher: __threadfence() -> read A[b] (canonical HIP
// last-block reduction pattern; atomicAdd is device-scope per guide G12).
// LDS epilogue buffers alias `tile` (no longer live) -> LDS stays 18.6 KB,
// 8 blocks/CU.
// ---------------------------------------------------------------------------
__global__ __launch_bounds__(256) void stats_gates_kernel(
        const float* __restrict__ x,
        const float* __restrict__ w1,
        const float* __restrict__ bn_gamma,
        const float* __restrict__ bn_beta,
        const float* __restrict__ bn_mean,
        const float* __restrict__ bn_var,
        const float* __restrict__ wh,
        const float* __restrict__ ww,
        float* __restrict__ A,
        float* __restrict__ gates,
        unsigned int* __restrict__ cnt) {
    const int bc = blockIdx.x;                       // b*Cn + c
    const int b  = bc >> 8;
    const float* xp = x + (size_t)bc * (Hn * Wn);
    __shared__ float tile[Hn * 65];                  // pitch 65: row & col conflict-free
    __shared__ float pmax[256], psum[256];
    const int t = threadIdx.x;

    // load 64x64 tile, float4-vectorized, coalesced (normal loads: WANT x in
    // L2/L3 for apply_kernel's re-read)
#pragma unroll
    for (int k = 0; k < 4; ++k) {
        int i4  = t + 256 * k;                       // float4 index 0..1023
        int idx = i4 * 4;
        int h = idx >> 6;
        int w = idx & 63;
        float4 v = ((const float4*)xp)[i4];
        float* dst = &tile[h * 65 + w];
        dst[0] = v.x; dst[1] = v.y; dst[2] = v.z; dst[3] = v.w;
    }
    __syncthreads();

    // half-range partial reductions (32 serial LDS reads each)
    {
        const int wv   = t >> 6;                     // wave id 0..3
        const int lane = t & 63;
        float m = -INFINITY, sm = 0.f;
        if ((wv & 1) == 0) {                         // waves 0,2: row lane, half (wv>>1)
            const int h = lane, w0 = (wv >> 1) * 32;
#pragma unroll 8
            for (int w = w0; w < w0 + 32; ++w) {
                float v = tile[h * 65 + w];
                m = fmaxf(m, v); sm += v;
            }
        } else {                                     // waves 1,3: col lane, half (wv>>1)
            const int w = lane, h0 = (wv >> 1) * 32;
#pragma unroll 8
            for (int h = h0; h < h0 + 32; ++h) {
                float v = tile[h * 65 + w];
                m = fmaxf(m, v); sm += v;
            }
        }
        pmax[t] = m; psum[t] = sm;
    }
    __syncthreads();

    if (t < 128) {
        float red_max = fmaxf(pmax[t], pmax[t + 128]);
        float red_sum = psum[t] + psum[t + 128];
        // softmax across the 64 lanes of this wave (wave0 = rows, wave1 = cols)
        float m = red_max;
#pragma unroll
        for (int off = 32; off > 0; off >>= 1) m = fmaxf(m, __shfl_xor(m, off));
        float e = __expf(red_max - m);
        float se = e;
#pragma unroll
        for (int off = 32; off > 0; off >>= 1) se += __shfl_xor(se, off);
        float a = (red_sum + e / se) * (1.0f / 64.0f);
        A[(size_t)bc * 128 + t] = a;
    }

    // ---- last-block-per-b gates epilogue -------------------------------
    __threadfence();                                 // release A writes (device scope)
    __syncthreads();
    __shared__ unsigned int tkt;
    if (t == 0) tkt = atomicAdd(&cnt[b], 1u);        // device-scope atomic
    __syncthreads();
    if (tkt != Cn - 1) return;                       // not the last arriver for b

    __threadfence();                                 // acquire: see all A[b] writes

    float* red = tile;                               // [MIP][128], aliases tile
    float* ysl = tile + MIP * 128;                   // [MIP][128]
    const int s  = t & 127;
    const int g2 = t >> 7;                           // c-half 0/1

    const float* Ab = A + (size_t)b * Cn * 128;
    float acc[MIP];
#pragma unroll
    for (int m = 0; m < MIP; ++m) acc[m] = 0.f;
#pragma unroll 4
    for (int i = 0; i < 128; ++i) {
        const int cc = g2 * 128 + i;
        float a = Ab[(size_t)cc * 128 + s];          // coalesced over s (L2-hot)
#pragma unroll
        for (int m = 0; m < MIP; ++m)
            acc[m] += w1[m * Cn + cc] * a;           // wave-uniform scalar load
    }
    if (g2 == 1) {
#pragma unroll
        for (int m = 0; m < MIP; ++m) red[m * 128 + s] = acc[m];
    }
    __syncthreads();
    if (g2 == 0) {
#pragma unroll
        for (int m = 0; m < MIP; ++m) {
            float v = acc[m] + red[m * 128 + s];
            float sc = bn_gamma[m] * rsqrtf(bn_var[m] + BN_EPS);
            float sh = bn_beta[m] - bn_mean[m] * sc;
            v = v * sc + sh;
            v = v * fminf(fmaxf(v + 3.0f, 0.0f), 6.0f) * (1.0f / 6.0f); // hswish
            ysl[m * 128 + s] = v;
        }
    }
    __syncthreads();

    // gates for all 256 c of this b, split c-range over the two thread halves
    float yv[MIP];
#pragma unroll
    for (int m = 0; m < MIP; ++m) yv[m] = ysl[m * 128 + s];  // conflict-free
    const float* w2base = (s < 64) ? wh : ww;        // wave-uniform (s = t&127)
    float* gb = gates + (size_t)b * Cn * 128;
    for (int i = 0; i < 128; ++i) {
        const int c = g2 * 128 + i;
        const float* w2 = w2base + c * MIP;          // wave-uniform scalar loads
        float g = 0.f;
#pragma unroll
        for (int m = 0; m < MIP; ++m) g += w2[m] * yv[m];
        gb[(size_t)c * 128 + s] = 1.0f / (1.0f + __expf(-g));  // coalesced over s
    }
}

// ---------------------------------------------------------------------------
// Kernel 2: pure-stream apply.
//   out[b,c,h,w] = x[b,c,h,w] * g[bc][h] * g[bc][64+w]
// Gate row (512 B) and all 4 x nontemporal loads are issued together: ONE
// memory round trip per block, no dependent dot-product prologue.
//   NT loads for x (last use, L3-hit expected) + NT stores (never re-read,
//   no-allocate keeps x resident in L3 while we stream).
// ---------------------------------------------------------------------------
__global__ __launch_bounds__(256) void apply_kernel(const float* __restrict__ x,
                                                    const float* __restrict__ gates,
                                                    float* __restrict__ out) {
    const int bc = blockIdx.x;
    const float* xp = x + (size_t)bc * (Hn * Wn);
    float* op = out + (size_t)bc * (Hn * Wn);
    const int t = threadIdx.x;

    __shared__ float gs[128];                        // [0,64): g_h, [64,128): g_w

    float gv = 0.f;
    if (t < 128) gv = gates[(size_t)bc * 128 + t];   // issued first (oldest vmcnt)

    vfloat4 v[4];
#pragma unroll
    for (int k = 0; k < 4; ++k)                      // in flight concurrently w/ gv
        v[k] = __builtin_nontemporal_load(&((const vfloat4*)xp)[t + 256 * k]);

    if (t < 128) gs[t] = gv;                         // waits vmcnt(4): only gv
    __syncthreads();

#pragma unroll
    for (int k = 0; k < 4; ++k) {
        int idx = (t + 256 * k) * 4;
        int h = idx >> 6;
        int w = idx & 63;                            // w % 4 == 0 -> aligned b128
        float gh = gs[h];
        float4 gw = *(const float4*)&gs[64 + w];     // one ds_read_b128
        vfloat4 r;
        r.x = v[k].x * gh * gw.x;
        r.y = v[k].y * gh * gw.y;
        r.z = v[k].z * gh * gw.z;
        r.w = v[k].w * gh * gw.w;
        __builtin_nontemporal_store(r, &((vfloat4*)op)[t + 256 * k]);
    }
}

extern "C" void kernel_launch(void* const* d_in, const int* in_sizes, int n_in,
                              void* d_out, int out_size, void* d_ws, size_t ws_size,
                              hipStream_t stream) {
    const float* x        = (const float*)d_in[0];
    const float* w1       = (const float*)d_in[1];
    const float* bn_gamma = (const float*)d_in[2];
    const float* bn_beta  = (const float*)d_in[3];
    const float* bn_mean  = (const float*)d_in[4];
    const float* bn_var   = (const float*)d_in[5];
    const float* wh       = (const float*)d_in[6];
    const float* ww       = (const float*)d_in[7];
    float* out = (float*)d_out;

    float* A     = (float*)d_ws;                           // Bn*Cn*128 floats = 4 MiB
    float* gates = A + (size_t)Bn * Cn * 128;              // Bn*Cn*128 floats = 4 MiB
    unsigned int* cnt = (unsigned int*)(gates + (size_t)Bn * Cn * 128);  // Bn u32

    hipMemsetAsync(cnt, 0, Bn * sizeof(unsigned int), stream);  // capture-legal
    stats_gates_kernel<<<Bn * Cn, 256, 0, stream>>>(x, w1, bn_gamma, bn_beta,
                                                    bn_mean, bn_var, wh, ww,
                                                    A, gates, cnt);
    apply_kernel<<<Bn * Cn, 256, 0, stream>>>(x, gates, out);
}

// Round 3
// 268.440 us; speedup vs baseline: 4.9683x; 4.9683x over previous
//
#include <hip/hip_runtime.h>
#include <math.h>

#define Bn 32
#define Cn 256
#define Hn 64
#define Wn 64
#define MIP 8
#define OUP 256
#define BN_EPS 1e-5f

typedef float vfloat4 __attribute__((ext_vector_type(4)));  // native vec for NT ld/st

// ---------------------------------------------------------------------------
// Kernel 1: per-(b,c) stats -> A[b][c][s], s in [0,128)
//   s<64:  a_h[h] = (rowsum[h] + softmax_h(rowmax)[h]) / 64
//   s>=64: a_w[w] = (colsum[w] + softmax_w(colmax)[w]) / 64
// (uses: mean_W(bias_h*bias_w) = bias_h/64 since softmax_w sums to 1)
// All 4 waves participate in the reduction: waves 0/2 split each row's w-range,
// waves 1/3 split each column's h-range; partials combine via LDS.
// HBM-read-bound (~134 MB): DS-pipe cost ~15 us < 21 us HBM floor.
// R2 LESSON (do not refuse): fusing the gates stage here via
// __threadfence()+atomic last-block pattern made this kernel 1161 us at 0.84%
// HBM / 0.7% VALUBusy -- device-scope fences on MI355X are chip-wide L2
// writeback events across 8 non-coherent XCD L2s; 8192 of them serialize the
// machine. Keep the stages as separate dispatches.
// ---------------------------------------------------------------------------
__global__ __launch_bounds__(256) void stats_kernel(const float* __restrict__ x,
                                                    float* __restrict__ A) {
    const int bc = blockIdx.x;                       // b*Cn + c
    const float* xp = x + (size_t)bc * (Hn * Wn);
    __shared__ float tile[Hn * 65];                  // pitch 65: row & col conflict-free
    __shared__ float pmax[256], psum[256];
    const int t = threadIdx.x;

    // load 64x64 tile, float4-vectorized, coalesced (normal loads: WANT x in
    // L2/L3 for apply_kernel's re-read)
#pragma unroll
    for (int k = 0; k < 4; ++k) {
        int i4  = t + 256 * k;                       // float4 index 0..1023
        int idx = i4 * 4;
        int h = idx >> 6;
        int w = idx & 63;
        float4 v = ((const float4*)xp)[i4];
        float* dst = &tile[h * 65 + w];
        dst[0] = v.x; dst[1] = v.y; dst[2] = v.z; dst[3] = v.w;
    }
    __syncthreads();

    // half-range partial reductions (32 serial LDS reads each)
    {
        const int wv   = t >> 6;                     // wave id 0..3
        const int lane = t & 63;
        float m = -INFINITY, sm = 0.f;
        if ((wv & 1) == 0) {                         // waves 0,2: row lane, half (wv>>1)
            const int h = lane, w0 = (wv >> 1) * 32;
#pragma unroll 8
            for (int w = w0; w < w0 + 32; ++w) {
                float v = tile[h * 65 + w];
                m = fmaxf(m, v); sm += v;
            }
        } else {                                     // waves 1,3: col lane, half (wv>>1)
            const int w = lane, h0 = (wv >> 1) * 32;
#pragma unroll 8
            for (int h = h0; h < h0 + 32; ++h) {
                float v = tile[h * 65 + w];
                m = fmaxf(m, v); sm += v;
            }
        }
        pmax[t] = m; psum[t] = sm;
    }
    __syncthreads();

    if (t < 128) {
        float red_max = fmaxf(pmax[t], pmax[t + 128]);
        float red_sum = psum[t] + psum[t + 128];
        // softmax across the 64 lanes of this wave (wave0 = rows, wave1 = cols)
        float m = red_max;
#pragma unroll
        for (int off = 32; off > 0; off >>= 1) m = fmaxf(m, __shfl_xor(m, off));
        float e = __expf(red_max - m);
        float se = e;
#pragma unroll
        for (int off = 32; off > 0; off >>= 1) se += __shfl_xor(se, off);
        float a = (red_sum + e / se) * (1.0f / 64.0f);
        A[(size_t)bc * 128 + t] = a;
    }
}

// ---------------------------------------------------------------------------
// Kernel 2 (tiny): yact[b][m][s] = hswish(BN(sum_c w1[m][c] * A[b][c][s]))
//   1024 threads: s = t&127, K=256 split 8-way (32 c per thread), LDS combine.
// ---------------------------------------------------------------------------
__global__ __launch_bounds__(1024) void ymix_kernel(const float* __restrict__ A,
                                                    const float* __restrict__ w1,
                                                    const float* __restrict__ bn_gamma,
                                                    const float* __restrict__ bn_beta,
                                                    const float* __restrict__ bn_mean,
                                                    const float* __restrict__ bn_var,
                                                    float* __restrict__ yact) {
    const int b = blockIdx.x;
    const int t = threadIdx.x;
    const int s     = t & 127;
    const int chunk = t >> 7;                        // 0..7

    const float* Ab = A + (size_t)b * Cn * 128;

    float acc[MIP];
#pragma unroll
    for (int m = 0; m < MIP; ++m) acc[m] = 0.f;

    const int c0 = chunk * 32;
    for (int c = c0; c < c0 + 32; ++c) {
        float a = Ab[(size_t)c * 128 + s];           // coalesced over s
#pragma unroll
        for (int m = 0; m < MIP; ++m)
            acc[m] += w1[m * Cn + c] * a;            // wave-uniform scalar load
    }

    __shared__ float red[7][MIP][128];               // chunks 1..7
    if (chunk > 0) {
#pragma unroll
        for (int m = 0; m < MIP; ++m) red[chunk - 1][m][s] = acc[m];
    }
    __syncthreads();
    if (chunk == 0) {
#pragma unroll
        for (int m = 0; m < MIP; ++m) {
            float v = acc[m];
#pragma unroll
            for (int k = 0; k < 7; ++k) v += red[k][m][s];
            float sc = bn_gamma[m] * rsqrtf(bn_var[m] + BN_EPS);
            float sh = bn_beta[m] - bn_mean[m] * sc;
            v = v * sc + sh;
            v = v * fminf(fmaxf(v + 3.0f, 0.0f), 6.0f) * (1.0f / 6.0f); // hswish
            yact[(size_t)b * (MIP * 128) + m * 128 + s] = v;
        }
    }
}

// ---------------------------------------------------------------------------
// Kernel 3: per-(b,c) gate-compute + apply.
//   gs[s] = sigmoid(sum_m W2[c][m] * yact[b][m][s])  (W2 = wh for s<64, ww else)
//   out[b,c,h,w] = x[b,c,h,w] * gs[h] * gs[64+w]
//   NT loads for x (last use) + NT stores for out (never re-read).
// (R1 tested a precomputed-gates variant removing the per-block dot product:
//  neutral within noise -- per-block latency chains are hidden by TLP at 8192
//  blocks. Keep the simpler form.)
// ---------------------------------------------------------------------------
__global__ __launch_bounds__(256) void apply_kernel(const float* __restrict__ x,
                                                    const float* __restrict__ yact,
                                                    const float* __restrict__ wh,
                                                    const float* __restrict__ ww,
                                                    float* __restrict__ out) {
    const int bc = blockIdx.x;
    const int b  = bc >> 8;
    const int c  = bc & 255;
    const float* xp = x + (size_t)bc * (Hn * Wn);
    float* op = out + (size_t)bc * (Hn * Wn);

    __shared__ float gs[128];                        // [0,64): g_h, [64,128): g_w
    const int t = threadIdx.x;
    if (t < 128) {
        const float* w2row = (t < 64) ? (wh + c * MIP) : (ww + c * MIP); // wave-uniform
        const float* yb = yact + (size_t)b * (MIP * 128);
        float g = 0.f;
#pragma unroll
        for (int m = 0; m < MIP; ++m)
            g += w2row[m] * yb[m * 128 + t];         // coalesced over t
        gs[t] = 1.0f / (1.0f + __expf(-g));
    }
    __syncthreads();

#pragma unroll
    for (int k = 0; k < 4; ++k) {
        int i4  = t + 256 * k;
        int idx = i4 * 4;
        int h = idx >> 6;
        int w = idx & 63;                            // w % 4 == 0 -> aligned b128
        vfloat4 v = __builtin_nontemporal_load(&((const vfloat4*)xp)[i4]);
        float gh = gs[h];
        float4 gw = *(const float4*)&gs[64 + w];     // one ds_read_b128
        vfloat4 r;
        r.x = v.x * gh * gw.x;
        r.y = v.y * gh * gw.y;
        r.z = v.z * gh * gw.z;
        r.w = v.w * gh * gw.w;
        __builtin_nontemporal_store(r, &((vfloat4*)op)[i4]);
    }
}

extern "C" void kernel_launch(void* const* d_in, const int* in_sizes, int n_in,
                              void* d_out, int out_size, void* d_ws, size_t ws_size,
                              hipStream_t stream) {
    const float* x        = (const float*)d_in[0];
    const float* w1       = (const float*)d_in[1];
    const float* bn_gamma = (const float*)d_in[2];
    const float* bn_beta  = (const float*)d_in[3];
    const float* bn_mean  = (const float*)d_in[4];
    const float* bn_var   = (const float*)d_in[5];
    const float* wh       = (const float*)d_in[6];
    const float* ww       = (const float*)d_in[7];
    float* out = (float*)d_out;

    float* A    = (float*)d_ws;                            // Bn*Cn*128 floats = 4 MiB
    float* yact = A + (size_t)Bn * Cn * 128;               // Bn*MIP*128 floats = 128 KiB

    stats_kernel<<<Bn * Cn, 256, 0, stream>>>(x, A);
    ymix_kernel<<<Bn, 1024, 0, stream>>>(A, w1, bn_gamma, bn_beta, bn_mean,
                                         bn_var, yact);
    apply_kernel<<<Bn * Cn, 256, 0, stream>>>(x, yact, wh, ww, out);
}